// Round 8
// baseline (179.476 us; speedup 1.0000x reference)
//
#include <hip/hip_runtime.h>
#include <hip/hip_bf16.h>

// Fused attention: q = x1@W^T+b, k = x2@W^T+b, scores = (q k^T)*8,
// p = softmax(scores), out = p @ x2.  B=4, S=T=4096, F=127, D=64, fp32 io.
//
// Round 7: the attn kernel was L2-BW bound (1.05 GB L2 traffic, ~30 us
// floor). Fix: LDS pair-sharing -- waves (sub0,qtr)/(sub1,qtr) need the
// SAME K/xv tile; stage it in LDS once (sub0 stages K, sub1 stages xv;
// reg-staged ds_write; both read) -> 0.5 GB. Plus: skip-tile fast path
// (pmax < m-26 -> tile contributes ~0; skip exp/pack/PV), single-chain QK
// (acc regs down -> arch headroom; 8-wave block budget is 256 COMBINED).
//
// ws: qhf [0,2MB) | qlf [2,4) | khf [4,6) | klf [6,8) | x2tf [8,12)

typedef __bf16 bf16x8 __attribute__((ext_vector_type(8)));
typedef float f32x16 __attribute__((ext_vector_type(16)));

#define S_DIM 4096
#define F_DIM 127
#define QSCALE 11.5415603271f  // 8 * log2(e)
#define THR 11.0f              // defer-max threshold (log2 units)
#define SKIP 26.0f             // tile-skip threshold: p < 2^-26 -> negligible

static __device__ __forceinline__ unsigned cvt_pk_bf16(float lo, float hi) {
  unsigned r;
  asm("v_cvt_pk_bf16_f32 %0, %1, %2" : "=v"(r) : "v"(lo), "v"(hi));
  return r;
}
static __device__ __forceinline__ float exp2_fast(float x) {
  float r;
  asm("v_exp_f32 %0, %1" : "=v"(r) : "v"(x));
  return r;
}
static __device__ __forceinline__ float m3(float a, float b, float c) {
  return fmaxf(fmaxf(a, b), c);  // clang fuses to v_max3_f32
}
static __device__ __forceinline__ bf16x8 mk_bf16x8(unsigned w0, unsigned w1,
                                                   unsigned w2, unsigned w3) {
  unsigned t[4] = {w0, w1, w2, w3};
  bf16x8 r;
  __builtin_memcpy(&r, t, 16);
  return r;
}
static __device__ __forceinline__ bf16x8 u4_bf16x8(uint4 v) {
  bf16x8 r;
  __builtin_memcpy(&r, &v, 16);
  return r;
}
// split 8 fp32 -> bf16 hi frag + bf16 lo frag
static __device__ __forceinline__ void split8(float4 a, float4 b, bf16x8& hv,
                                              bf16x8& lv) {
  const unsigned h0 = cvt_pk_bf16(a.x, a.y);
  const unsigned h1 = cvt_pk_bf16(a.z, a.w);
  const unsigned h2 = cvt_pk_bf16(b.x, b.y);
  const unsigned h3 = cvt_pk_bf16(b.z, b.w);
  const unsigned l0 = cvt_pk_bf16(a.x - __uint_as_float(h0 << 16),
                                  a.y - __uint_as_float(h0 & 0xffff0000u));
  const unsigned l1 = cvt_pk_bf16(a.z - __uint_as_float(h1 << 16),
                                  a.w - __uint_as_float(h1 & 0xffff0000u));
  const unsigned l2 = cvt_pk_bf16(b.x - __uint_as_float(h2 << 16),
                                  b.y - __uint_as_float(h2 & 0xffff0000u));
  const unsigned l3 = cvt_pk_bf16(b.z - __uint_as_float(h3 << 16),
                                  b.w - __uint_as_float(h3 & 0xffff0000u));
  hv = mk_bf16x8(h0, h1, h2, h3);
  lv = mk_bf16x8(l0, l1, l2, l3);
}

// -------------------------------------------------------------------- prep
// grid 1280 x 256. (identical to round 5/6 -- proven, ~10 us)
//  blocks [0,256): projection. [0,128)->Q from x1, [128,256)->K from x2.
//  blocks [256,1280): x2 -> PV-A fragments (f==127 pad = 1.0 -> PV
//    accumulates l = sum(p) into acc row 127 for free).
__global__ __launch_bounds__(256) void prep_kernel(
    const float* __restrict__ x1, const float* __restrict__ x2,
    const float* __restrict__ W, const float* __restrict__ bias,
    uint4* __restrict__ qhf, uint4* __restrict__ qlf,
    uint4* __restrict__ khf, uint4* __restrict__ klf,
    uint4* __restrict__ x2tf) {
  __shared__ unsigned shbuf[8448];  // 33792 B: W[64][132] fp32 / kstage[4][2112]
  const int tid = threadIdx.x;
  const int bi = blockIdx.x;

  if (bi >= 256) {  // ---------------- x2 repack path
    const int ri = bi - 256;
    const int b = ri >> 8;
    const int tt = ri & 255;
    const int fb = tid >> 6;
    const int l = tid & 63;
    const int t0 = tt * 16 + ((l >> 5) << 3);
    const int f = fb * 32 + (l & 31);
    const float* src = x2 + ((long)b * S_DIM + t0) * F_DIM + f;
    unsigned w[4];
#pragma unroll
    for (int g = 0; g < 4; ++g) {
      const float v0 = (f < F_DIM) ? src[(long)(2 * g) * F_DIM] : 1.0f;
      const float v1 = (f < F_DIM) ? src[(long)(2 * g + 1) * F_DIM] : 1.0f;
      w[g] = cvt_pk_bf16(v0, v1);
    }
    x2tf[((long)(b * 256 + tt) * 4 + fb) * 64 + l] =
        make_uint4(w[0], w[1], w[2], w[3]);
    return;
  }

  // ---------------- projection path
  float* shw = (float*)shbuf;  // [64][132]
  for (int idx = tid; idx < 64 * 128; idx += 256) {
    const int d = idx >> 7;
    const int f = idx & 127;
    shw[d * 132 + f] = (f < F_DIM) ? W[d * F_DIM + f] : 0.f;
  }
  __syncthreads();

  const int wave = tid >> 6;
  const int lane = tid & 63;
  const int arow = lane & 31;
  const int half = lane >> 5;
  const bool isK = bi >= 128;
  const float* x = isK ? x2 : x1;
  const int grow0 = (bi & 127) * 128 + wave * 32;
  const float* xrow = x + (long)(grow0 + arow) * F_DIM;

  bf16x8 xh[8], xl[8];
#pragma unroll
  for (int kk = 0; kk < 8; ++kk) {
    const int f0 = kk * 16 + half * 8;
    float4 a, b;
    a.x = (f0 + 0 < F_DIM) ? xrow[f0 + 0] : 0.f;
    a.y = (f0 + 1 < F_DIM) ? xrow[f0 + 1] : 0.f;
    a.z = (f0 + 2 < F_DIM) ? xrow[f0 + 2] : 0.f;
    a.w = (f0 + 3 < F_DIM) ? xrow[f0 + 3] : 0.f;
    b.x = (f0 + 4 < F_DIM) ? xrow[f0 + 4] : 0.f;
    b.y = (f0 + 5 < F_DIM) ? xrow[f0 + 5] : 0.f;
    b.z = (f0 + 6 < F_DIM) ? xrow[f0 + 6] : 0.f;
    b.w = (f0 + 7 < F_DIM) ? xrow[f0 + 7] : 0.f;
    split8(a, b, xh[kk], xl[kk]);
  }

  f32x16 acc0, acc1;
#pragma unroll
  for (int r = 0; r < 16; ++r) {
    acc0[r] = 0.f;
    acc1[r] = 0.f;
  }
#pragma unroll
  for (int kk = 0; kk < 8; ++kk) {
    const int f0 = kk * 16 + half * 8;
    bf16x8 wh0, wl0, wh1, wl1;
    {
      const float4 a = *(const float4*)&shw[arow * 132 + f0];
      const float4 b = *(const float4*)&shw[arow * 132 + f0 + 4];
      split8(a, b, wh0, wl0);
    }
    {
      const float4 a = *(const float4*)&shw[(32 + arow) * 132 + f0];
      const float4 b = *(const float4*)&shw[(32 + arow) * 132 + f0 + 4];
      split8(a, b, wh1, wl1);
    }
    acc0 = __builtin_amdgcn_mfma_f32_32x32x16_bf16(xh[kk], wh0, acc0, 0, 0, 0);
    acc0 = __builtin_amdgcn_mfma_f32_32x32x16_bf16(xh[kk], wl0, acc0, 0, 0, 0);
    acc0 = __builtin_amdgcn_mfma_f32_32x32x16_bf16(xl[kk], wh0, acc0, 0, 0, 0);
    acc1 = __builtin_amdgcn_mfma_f32_32x32x16_bf16(xh[kk], wh1, acc1, 0, 0, 0);
    acc1 = __builtin_amdgcn_mfma_f32_32x32x16_bf16(xh[kk], wl1, acc1, 0, 0, 0);
    acc1 = __builtin_amdgcn_mfma_f32_32x32x16_bf16(xl[kk], wh1, acc1, 0, 0, 0);
  }
  __syncthreads();  // W staging dead; reuse shbuf as kstage

  unsigned* kst = shbuf + wave * 2112;  // 32*66, stride 66 (2-way free)
#pragma unroll
  for (int dt = 0; dt < 2; ++dt) {
    const f32x16 acc = dt ? acc1 : acc0;
    const int d = dt * 32 + arow;
    const float bd = bias[d];
#pragma unroll
    for (int r = 0; r < 16; r += 2) {
      const int row0 = (r & 3) + 8 * (r >> 2) + 4 * half;  // rows row0,row0+1
      float v0 = acc[r] + bd;
      float v1 = acc[r + 1] + bd;
      if (!isK) {
        v0 *= QSCALE;
        v1 *= QSCALE;
      }
      const unsigned h = cvt_pk_bf16(v0, v1);
      const float l0 = v0 - __uint_as_float(h << 16);
      const float l1 = v1 - __uint_as_float(h & 0xffff0000u);
      const unsigned l = cvt_pk_bf16(l0, l1);
      kst[row0 * 66 + d] = (h & 0xffffu) | (l << 16);
      kst[(row0 + 1) * 66 + d] = (h >> 16) | (l & 0xffff0000u);
    }
  }

  const int b = grow0 >> 12;
  const int tile = (grow0 & (S_DIM - 1)) >> 5;
  uint4* dh = (isK ? khf : qhf) + ((long)(b * 128 + tile) * 4) * 64 + lane;
  uint4* dl = (isK ? klf : qlf) + ((long)(b * 128 + tile) * 4) * 64 + lane;
#pragma unroll
  for (int kk = 0; kk < 4; ++kk) {
    const int d0 = kk * 16 + half * 8;
    unsigned w[8];
#pragma unroll
    for (int j = 0; j < 8; ++j) w[j] = kst[arow * 66 + d0 + j];
    unsigned hw[4], lw[4];
#pragma unroll
    for (int g = 0; g < 4; ++g) {
      hw[g] = (w[2 * g] & 0xffffu) | (w[2 * g + 1] << 16);
      lw[g] = (w[2 * g] >> 16) | (w[2 * g + 1] & 0xffff0000u);
    }
    dh[kk * 64] = make_uint4(hw[0], hw[1], hw[2], hw[3]);
    dl[kk * 64] = make_uint4(lw[0], lw[1], lw[2], lw[3]);
  }
}

// ------------------------------------------------------------------ attention
// grid 256 x 512 (1 block/CU). XCD-swizzled. wave w: q-subtile sub=w&1,
// key-quarter qtr=w>>1 (32 tiles). Per iter, the sub-pair shares its tile
// via LDS: sub0 stages K (8 KB), sub1 stages xv (8 KB); both read. L2
// traffic per CU-iter: 64 KB (was 128). Double-buffered, 1 barrier/iter.
// LDS arena 128 KB: [buf0 64K | buf1 64K]; merge aliases buf0 afterwards.
__global__ __launch_bounds__(512, 1) void attn_kernel(
    const uint4* __restrict__ qhf, const uint4* __restrict__ qlf,
    const uint4* __restrict__ khf, const uint4* __restrict__ klf,
    const uint4* __restrict__ x2tf, float* __restrict__ out) {
  __shared__ __align__(16) char arena[131072];
  const int tid = threadIdx.x;
  const int lane = tid & 63;
  const int wave = tid >> 6;
  const int col = lane & 31;
  const int half = lane >> 5;
  const int sub = wave & 1;
  const int qtr = wave >> 1;
  const int bi = blockIdx.x;
  const int xcd = bi & 7;
  const int slot = bi >> 3;
  const int L = (xcd >> 1) * 64 + slot * 2 + (xcd & 1);
  const int b = L >> 6;
  const int q0 = (L & 63) << 6;

  // Q fragments (pre-split): subtile's 32 q-rows.
  const int qtile = ((q0 + sub * 32) & (S_DIM - 1)) >> 5;
  bf16x8 qh[4], ql[4];
#pragma unroll
  for (int kk = 0; kk < 4; ++kk) {
    qh[kk] = u4_bf16x8(qhf[((long)(b * 128 + qtile) * 4 + kk) * 64 + lane]);
    ql[kk] = u4_bf16x8(qlf[((long)(b * 128 + qtile) * 4 + kk) * 64 + lane]);
  }

  const uint4* khfp = khf + (long)b * 128 * 4 * 64;
  const uint4* klfp = klf + (long)b * 128 * 4 * 64;
  const uint4* xfp = x2tf + (long)b * 256 * 4 * 64;

  // LDS layout per buffer c: c*65536 + qtr*16384 + { K: kk*1024 (kh),
  // 4096+kk*1024 (kl) ; xv: 8192 + (kf*4+fb)*1024 }, + lane*16 within chunk.
  char* const myqtr = arena + qtr * 16384;

  auto issue = [&](int t, uint4(&sv)[8]) {
    if (sub == 0) {
#pragma unroll
      for (int kk = 0; kk < 4; ++kk) {
        sv[kk] = khfp[(t * 4 + kk) * 64 + lane];
        sv[4 + kk] = klfp[(t * 4 + kk) * 64 + lane];
      }
    } else {
#pragma unroll
      for (int j = 0; j < 8; ++j)
        sv[j] = xfp[((t * 2 + (j >> 2)) * 4 + (j & 3)) * 64 + lane];
    }
  };
  auto store = [&](int c, const uint4(&sv)[8]) {
    char* dst = myqtr + c * 65536 + (sub ? 8192 : 0) + lane * 16;
#pragma unroll
    for (int j = 0; j < 8; ++j) *(uint4*)(dst + j * 1024) = sv[j];
  };

  f32x16 a0, a1, a2, a3;
#pragma unroll
  for (int r = 0; r < 16; ++r) {
    a0[r] = 0.f; a1[r] = 0.f; a2[r] = 0.f; a3[r] = 0.f;
  }
  float m = -INFINITY;

  {  // prologue: stage tile (i=0) into buf 0
    uint4 sv[8];
    issue(qtr, sv);
    store(0, sv);
  }
  __syncthreads();

  for (int i = 0; i < 32; ++i) {
    const int c = i & 1;
    const bool more = (i < 31);
    uint4 sv[8];
    if (more) issue(((i + 1) << 2) + qtr, sv);  // loads hide under compute

    const char* src = myqtr + c * 65536 + lane * 16;
    // S^T = K . Q^T (3-term split-bf16), single 12-chain; operands from LDS
    f32x16 st;
#pragma unroll
    for (int r = 0; r < 16; ++r) st[r] = 0.f;
    __builtin_amdgcn_s_setprio(1);
#pragma unroll
    for (int kk = 0; kk < 4; ++kk) {
      const bf16x8 kv = *(const bf16x8*)(src + kk * 1024);
      const bf16x8 lv = *(const bf16x8*)(src + 4096 + kk * 1024);
      st = __builtin_amdgcn_mfma_f32_32x32x16_bf16(kv, qh[kk], st, 0, 0, 0);
      st = __builtin_amdgcn_mfma_f32_32x32x16_bf16(kv, ql[kk], st, 0, 0, 0);
      st = __builtin_amdgcn_mfma_f32_32x32x16_bf16(lv, qh[kk], st, 0, 0, 0);
    }
    __builtin_amdgcn_s_setprio(0);

    // row max: max3 tree + cross-half shuffle
    const float e0 = m3(st[0], st[1], st[2]);
    const float e1 = m3(st[3], st[4], st[5]);
    const float e2 = m3(st[6], st[7], st[8]);
    const float e3 = m3(st[9], st[10], st[11]);
    const float e4 = m3(st[12], st[13], st[14]);
    float pmax = fmaxf(m3(e0, e1, e2), m3(e3, e4, st[15]));
    pmax = fmaxf(pmax, __shfl_xor(pmax, 32));
    if (__any(pmax > m + THR)) {  // defer-max: rescale rarely
      const float mnew = fmaxf(m, pmax);
      const float sc = exp2_fast(m - mnew);
#pragma unroll
      for (int r = 0; r < 16; ++r) {
        a0[r] *= sc; a1[r] *= sc; a2[r] *= sc; a3[r] *= sc;
      }
      m = mnew;
    }
    // skip-tile fast path: whole tile's p < 2^-26 -> contributes nothing
    if (__any(pmax > m - SKIP)) {
      uint4 xv[8];
#pragma unroll
      for (int j = 0; j < 8; ++j)
        xv[j] = *(const uint4*)(src + 8192 + j * 1024);
      unsigned pg[4][2];
#pragma unroll
      for (int g = 0; g < 4; ++g) {
        pg[g][0] = cvt_pk_bf16(exp2_fast(st[4 * g + 0] - m),
                               exp2_fast(st[4 * g + 1] - m));
        pg[g][1] = cvt_pk_bf16(exp2_fast(st[4 * g + 2] - m),
                               exp2_fast(st[4 * g + 3] - m));
      }
      __builtin_amdgcn_s_setprio(1);
#pragma unroll
      for (int kk = 0; kk < 2; ++kk) {
        unsigned x0 = pg[2 * kk][0], y0 = pg[2 * kk + 1][0];
        unsigned x1 = pg[2 * kk][1], y1 = pg[2 * kk + 1][1];
        asm("v_permlane32_swap_b32 %0, %1" : "+v"(x0), "+v"(y0));
        asm("v_permlane32_swap_b32 %0, %1" : "+v"(x1), "+v"(y1));
        const bf16x8 pf = mk_bf16x8(x0, x1, y0, y1);
        a0 = __builtin_amdgcn_mfma_f32_32x32x16_bf16(u4_bf16x8(xv[kk * 4 + 0]),
                                                     pf, a0, 0, 0, 0);
        a1 = __builtin_amdgcn_mfma_f32_32x32x16_bf16(u4_bf16x8(xv[kk * 4 + 1]),
                                                     pf, a1, 0, 0, 0);
        a2 = __builtin_amdgcn_mfma_f32_32x32x16_bf16(u4_bf16x8(xv[kk * 4 + 2]),
                                                     pf, a2, 0, 0, 0);
        a3 = __builtin_amdgcn_mfma_f32_32x32x16_bf16(u4_bf16x8(xv[kk * 4 + 3]),
                                                     pf, a3, 0, 0, 0);
      }
      __builtin_amdgcn_s_setprio(0);
    }
    if (more) store(c ^ 1, sv);  // write-late: HBM/L2 latency already hidden
    __syncthreads();             // staged data + all reads of buf[c] done
  }

  // -------- merge: aliased onto arena (all staging reads completed).
  float* accb = (float*)arena;               // [2][128*33] = 33792 B
  float* mb = (float*)(arena + 33792);       // [8][32]
  if (lane < 32) mb[wave * 32 + col] = m;
  __syncthreads();
  float mstar = mb[sub * 32 + col];
#pragma unroll
  for (int w = 1; w < 4; ++w) mstar = fmaxf(mstar, mb[(sub + 2 * w) * 32 + col]);
  const float wsc = exp2_fast(m - mstar);
  float* buf = accb + sub * (128 * 33);
  auto emit = [&](const f32x16& av, int fb, bool first) {
#pragma unroll
    for (int r = 0; r < 16; ++r) {
      const int f = fb * 32 + (r & 3) + 8 * (r >> 2) + 4 * half;
      const float v = av[r] * wsc;
      if (first) buf[f * 33 + col] = v;
      else buf[f * 33 + col] += v;
    }
  };
  for (int p = 0; p < 4; ++p) {
    if (qtr == p) {
      const bool first = (p == 0);
      emit(a0, 0, first);
      emit(a1, 1, first);
      emit(a2, 2, first);
      emit(a3, 3, first);
    }
    __syncthreads();
  }

  // readout: 512 threads, q64 = tid>>3 (64 rows), fg = tid&7 (16 f each)
  const int q64 = tid >> 3;
  const int fg = tid & 7;
  const int s2 = q64 >> 5;
  const int qq = q64 & 31;
  const float inv = 1.0f / accb[s2 * (128 * 33) + 127 * 33 + qq];
  float* ob = out + ((long)(b * S_DIM + q0 + q64)) * F_DIM;
#pragma unroll
  for (int j = 0; j < 16; ++j) {
    const int f = fg * 16 + j;
    if (f < F_DIM) ob[f] = accb[s2 * (128 * 33) + f * 33 + qq] * inv;
  }
}

extern "C" void kernel_launch(void* const* d_in, const int* in_sizes, int n_in,
                              void* d_out, int out_size, void* d_ws,
                              size_t ws_size, hipStream_t stream) {
  const float* x1 = (const float*)d_in[0];
  const float* x2 = (const float*)d_in[1];
  const float* W = (const float*)d_in[2];
  const float* bias = (const float*)d_in[3];
  float* out = (float*)d_out;

  char* ws = (char*)d_ws;
  uint4* qhf = (uint4*)ws;                     // 2 MB
  uint4* qlf = (uint4*)(ws + (2l << 20));      // 2 MB
  uint4* khf = (uint4*)(ws + (4l << 20));      // 2 MB
  uint4* klf = (uint4*)(ws + (6l << 20));      // 2 MB
  uint4* x2tf = (uint4*)(ws + (8l << 20));     // 4 MB

  hipLaunchKernelGGL(prep_kernel, dim3(1280), dim3(256), 0, stream, x1, x2, W,
                     bias, qhf, qlf, khf, klf, x2tf);
  hipLaunchKernelGGL(attn_kernel, dim3(256), dim3(512), 0, stream, qhf, qlf,
                     khf, klf, x2tf, out);
}

// Round 9
// 78.253 us; speedup vs baseline: 2.2935x; 2.2935x over previous
//
#include <hip/hip_runtime.h>
#include <hip/hip_bf16.h>

// Fused attention: q = x1@W^T+b, k = x2@W^T+b, scores = (q k^T)*8,
// p = softmax(scores), out = p @ x2.  B=4, S=T=4096, F=127, D=64, fp32 io.
//
// Round 9: rebuild on the PROVEN register shape. Ledger decoded from R2-R8:
// launch_bounds 2nd arg behaves as blocks/CU; (256,2) = 8 waves/CU = 256
// combined regs/wave. R3's 256-thr attn (57.4us, arch 120, no spill) is the
// only structure with headroom. This round: that structure + pre-split Q +
// split QK chains (sa/sb, +16 AGPR, fits HERE) + skip-tile fast path
// (pmax < m-26 -> skip xv/exp/PV; deterministic, <=6e-5 of l) + setprio +
// max3 tree + batch-contiguous XCD swizzle. Prep unchanged (proven 10.5us).
//
// ws: qhf [0,2MB) | qlf [2,4) | khf [4,6) | klf [6,8) | x2tf [8,12)

typedef __bf16 bf16x8 __attribute__((ext_vector_type(8)));
typedef float f32x16 __attribute__((ext_vector_type(16)));

#define S_DIM 4096
#define F_DIM 127
#define QSCALE 11.5415603271f  // 8 * log2(e)
#define THR 11.0f              // defer-max threshold (log2 units)
#define SKIP 26.0f             // tile-skip: p < 2^-26 -> negligible

static __device__ __forceinline__ unsigned cvt_pk_bf16(float lo, float hi) {
  unsigned r;
  asm("v_cvt_pk_bf16_f32 %0, %1, %2" : "=v"(r) : "v"(lo), "v"(hi));
  return r;
}
static __device__ __forceinline__ float exp2_fast(float x) {
  float r;
  asm("v_exp_f32 %0, %1" : "=v"(r) : "v"(x));
  return r;
}
static __device__ __forceinline__ float m3(float a, float b, float c) {
  return fmaxf(fmaxf(a, b), c);  // clang fuses to v_max3_f32
}
static __device__ __forceinline__ bf16x8 mk_bf16x8(unsigned w0, unsigned w1,
                                                   unsigned w2, unsigned w3) {
  unsigned t[4] = {w0, w1, w2, w3};
  bf16x8 r;
  __builtin_memcpy(&r, t, 16);
  return r;
}
static __device__ __forceinline__ bf16x8 u4_bf16x8(uint4 v) {
  bf16x8 r;
  __builtin_memcpy(&r, &v, 16);
  return r;
}
// split 8 fp32 -> bf16 hi frag + bf16 lo frag
static __device__ __forceinline__ void split8(float4 a, float4 b, bf16x8& hv,
                                              bf16x8& lv) {
  const unsigned h0 = cvt_pk_bf16(a.x, a.y);
  const unsigned h1 = cvt_pk_bf16(a.z, a.w);
  const unsigned h2 = cvt_pk_bf16(b.x, b.y);
  const unsigned h3 = cvt_pk_bf16(b.z, b.w);
  const unsigned l0 = cvt_pk_bf16(a.x - __uint_as_float(h0 << 16),
                                  a.y - __uint_as_float(h0 & 0xffff0000u));
  const unsigned l1 = cvt_pk_bf16(a.z - __uint_as_float(h1 << 16),
                                  a.w - __uint_as_float(h1 & 0xffff0000u));
  const unsigned l2 = cvt_pk_bf16(b.x - __uint_as_float(h2 << 16),
                                  b.y - __uint_as_float(h2 & 0xffff0000u));
  const unsigned l3 = cvt_pk_bf16(b.z - __uint_as_float(h3 << 16),
                                  b.w - __uint_as_float(h3 & 0xffff0000u));
  hv = mk_bf16x8(h0, h1, h2, h3);
  lv = mk_bf16x8(l0, l1, l2, l3);
}

// -------------------------------------------------------------------- prep
// grid 1280 x 256. (proven ~10.5 us)
//  blocks [0,256): projection. [0,128)->Q from x1, [128,256)->K from x2.
//  blocks [256,1280): x2 -> PV-A fragments (f==127 pad = 1.0 -> PV
//    accumulates l = sum(p) into acc row 127 for free).
__global__ __launch_bounds__(256) void prep_kernel(
    const float* __restrict__ x1, const float* __restrict__ x2,
    const float* __restrict__ W, const float* __restrict__ bias,
    uint4* __restrict__ qhf, uint4* __restrict__ qlf,
    uint4* __restrict__ khf, uint4* __restrict__ klf,
    uint4* __restrict__ x2tf) {
  __shared__ unsigned shbuf[8448];  // 33792 B: W[64][132] fp32 / kstage[4][2112]
  const int tid = threadIdx.x;
  const int bi = blockIdx.x;

  if (bi >= 256) {  // ---------------- x2 repack path
    const int ri = bi - 256;
    const int b = ri >> 8;
    const int tt = ri & 255;
    const int fb = tid >> 6;
    const int l = tid & 63;
    const int t0 = tt * 16 + ((l >> 5) << 3);
    const int f = fb * 32 + (l & 31);
    const float* src = x2 + ((long)b * S_DIM + t0) * F_DIM + f;
    unsigned w[4];
#pragma unroll
    for (int g = 0; g < 4; ++g) {
      const float v0 = (f < F_DIM) ? src[(long)(2 * g) * F_DIM] : 1.0f;
      const float v1 = (f < F_DIM) ? src[(long)(2 * g + 1) * F_DIM] : 1.0f;
      w[g] = cvt_pk_bf16(v0, v1);
    }
    x2tf[((long)(b * 256 + tt) * 4 + fb) * 64 + l] =
        make_uint4(w[0], w[1], w[2], w[3]);
    return;
  }

  // ---------------- projection path
  float* shw = (float*)shbuf;  // [64][132]
  for (int idx = tid; idx < 64 * 128; idx += 256) {
    const int d = idx >> 7;
    const int f = idx & 127;
    shw[d * 132 + f] = (f < F_DIM) ? W[d * F_DIM + f] : 0.f;
  }
  __syncthreads();

  const int wave = tid >> 6;
  const int lane = tid & 63;
  const int arow = lane & 31;
  const int half = lane >> 5;
  const bool isK = bi >= 128;
  const float* x = isK ? x2 : x1;
  const int grow0 = (bi & 127) * 128 + wave * 32;
  const float* xrow = x + (long)(grow0 + arow) * F_DIM;

  bf16x8 xh[8], xl[8];
#pragma unroll
  for (int kk = 0; kk < 8; ++kk) {
    const int f0 = kk * 16 + half * 8;
    float4 a, b;
    a.x = (f0 + 0 < F_DIM) ? xrow[f0 + 0] : 0.f;
    a.y = (f0 + 1 < F_DIM) ? xrow[f0 + 1] : 0.f;
    a.z = (f0 + 2 < F_DIM) ? xrow[f0 + 2] : 0.f;
    a.w = (f0 + 3 < F_DIM) ? xrow[f0 + 3] : 0.f;
    b.x = (f0 + 4 < F_DIM) ? xrow[f0 + 4] : 0.f;
    b.y = (f0 + 5 < F_DIM) ? xrow[f0 + 5] : 0.f;
    b.z = (f0 + 6 < F_DIM) ? xrow[f0 + 6] : 0.f;
    b.w = (f0 + 7 < F_DIM) ? xrow[f0 + 7] : 0.f;
    split8(a, b, xh[kk], xl[kk]);
  }

  f32x16 acc0, acc1;
#pragma unroll
  for (int r = 0; r < 16; ++r) {
    acc0[r] = 0.f;
    acc1[r] = 0.f;
  }
#pragma unroll
  for (int kk = 0; kk < 8; ++kk) {
    const int f0 = kk * 16 + half * 8;
    bf16x8 wh0, wl0, wh1, wl1;
    {
      const float4 a = *(const float4*)&shw[arow * 132 + f0];
      const float4 b = *(const float4*)&shw[arow * 132 + f0 + 4];
      split8(a, b, wh0, wl0);
    }
    {
      const float4 a = *(const float4*)&shw[(32 + arow) * 132 + f0];
      const float4 b = *(const float4*)&shw[(32 + arow) * 132 + f0 + 4];
      split8(a, b, wh1, wl1);
    }
    acc0 = __builtin_amdgcn_mfma_f32_32x32x16_bf16(xh[kk], wh0, acc0, 0, 0, 0);
    acc0 = __builtin_amdgcn_mfma_f32_32x32x16_bf16(xh[kk], wl0, acc0, 0, 0, 0);
    acc0 = __builtin_amdgcn_mfma_f32_32x32x16_bf16(xl[kk], wh0, acc0, 0, 0, 0);
    acc1 = __builtin_amdgcn_mfma_f32_32x32x16_bf16(xh[kk], wh1, acc1, 0, 0, 0);
    acc1 = __builtin_amdgcn_mfma_f32_32x32x16_bf16(xh[kk], wl1, acc1, 0, 0, 0);
    acc1 = __builtin_amdgcn_mfma_f32_32x32x16_bf16(xl[kk], wh1, acc1, 0, 0, 0);
  }
  __syncthreads();  // W staging dead; reuse shbuf as kstage

  unsigned* kst = shbuf + wave * 2112;  // 32*66, stride 66 (2-way free)
#pragma unroll
  for (int dt = 0; dt < 2; ++dt) {
    const f32x16 acc = dt ? acc1 : acc0;
    const int d = dt * 32 + arow;
    const float bd = bias[d];
#pragma unroll
    for (int r = 0; r < 16; r += 2) {
      const int row0 = (r & 3) + 8 * (r >> 2) + 4 * half;  // rows row0,row0+1
      float v0 = acc[r] + bd;
      float v1 = acc[r + 1] + bd;
      if (!isK) {
        v0 *= QSCALE;
        v1 *= QSCALE;
      }
      const unsigned h = cvt_pk_bf16(v0, v1);
      const float l0 = v0 - __uint_as_float(h << 16);
      const float l1 = v1 - __uint_as_float(h & 0xffff0000u);
      const unsigned l = cvt_pk_bf16(l0, l1);
      kst[row0 * 66 + d] = (h & 0xffffu) | (l << 16);
      kst[(row0 + 1) * 66 + d] = (h >> 16) | (l & 0xffff0000u);
    }
  }

  const int b = grow0 >> 12;
  const int tile = (grow0 & (S_DIM - 1)) >> 5;
  uint4* dh = (isK ? khf : qhf) + ((long)(b * 128 + tile) * 4) * 64 + lane;
  uint4* dl = (isK ? klf : qlf) + ((long)(b * 128 + tile) * 4) * 64 + lane;
#pragma unroll
  for (int kk = 0; kk < 4; ++kk) {
    const int d0 = kk * 16 + half * 8;
    unsigned w[8];
#pragma unroll
    for (int j = 0; j < 8; ++j) w[j] = kst[arow * 66 + d0 + j];
    unsigned hw[4], lw[4];
#pragma unroll
    for (int g = 0; g < 4; ++g) {
      hw[g] = (w[2 * g] & 0xffffu) | (w[2 * g + 1] << 16);
      lw[g] = (w[2 * g] >> 16) | (w[2 * g + 1] & 0xffff0000u);
    }
    dh[kk * 64] = make_uint4(hw[0], hw[1], hw[2], hw[3]);
    dl[kk * 64] = make_uint4(lw[0], lw[1], lw[2], lw[3]);
  }
}

// ------------------------------------------------------------------ attention
// grid 512 x 256 (2 blocks/CU). block: 32 q-rows; wave w = key-quarter
// (32 tiles of 32 keys), private (m, acc), registers-only main loop,
// K double-buffer, split QK chains, skip-tile fast path, LDS merge.
// XCD swizzle: L = (bi&7)*64 + (bi>>3) -> each XCD serves ONE batch
// (2 MB working set < 4 MiB L2).
__global__ __launch_bounds__(256, 2) void attn_kernel(
    const uint4* __restrict__ qhf, const uint4* __restrict__ qlf,
    const uint4* __restrict__ khf, const uint4* __restrict__ klf,
    const uint4* __restrict__ x2tf, float* __restrict__ out) {
  const int tid = threadIdx.x;
  const int lane = tid & 63;
  const int wave = tid >> 6;  // key-quarter
  const int col = lane & 31;
  const int half = lane >> 5;
  const int bi = blockIdx.x;
  const int L = (bi & 7) * 64 + (bi >> 3);  // bijective, batch-contiguous/XCD
  const int b = L >> 7;
  const int qt = L & 127;
  const int q0 = qt << 5;

  // Q fragments (pre-split): this block's 32 q-rows.
  bf16x8 qh[4], ql[4];
#pragma unroll
  for (int kk = 0; kk < 4; ++kk) {
    qh[kk] = u4_bf16x8(qhf[((long)(b * 128 + qt) * 4 + kk) * 64 + lane]);
    ql[kk] = u4_bf16x8(qlf[((long)(b * 128 + qt) * 4 + kk) * 64 + lane]);
  }

  const uint4* khfp = khf + (long)b * 128 * 4 * 64;
  const uint4* klfp = klf + (long)b * 128 * 4 * 64;
  const uint4* xfp = x2tf + (long)b * 256 * 4 * 64;

  f32x16 a0, a1, a2, a3;
#pragma unroll
  for (int r = 0; r < 16; ++r) {
    a0[r] = 0.f; a1[r] = 0.f; a2[r] = 0.f; a3[r] = 0.f;
  }
  float m = -INFINITY;

  uint4 KA[8], KB[8];
#pragma unroll
  for (int kk = 0; kk < 4; ++kk) {
    KA[kk] = khfp[(wave * 4 + kk) * 64 + lane];
    KA[4 + kk] = klfp[(wave * 4 + kk) * 64 + lane];
  }

  auto body = [&](const uint4 (&C)[8], uint4 (&N)[8], int i) {
    const int tile = (i << 2) + wave;
    // prefetch next K tile into N (hides under QK+softmax)
    if (i < 31) {
      const int tn = ((i + 1) << 2) + wave;
#pragma unroll
      for (int kk = 0; kk < 4; ++kk) {
        N[kk] = khfp[(tn * 4 + kk) * 64 + lane];
        N[4 + kk] = klfp[(tn * 4 + kk) * 64 + lane];
      }
    }
    // S^T = K . Q^T: two INDEPENDENT 6-deep chains (sa, sb); st := sa+sb.
    f32x16 sa, sb;
#pragma unroll
    for (int r = 0; r < 16; ++r) {
      sa[r] = 0.f;
      sb[r] = 0.f;
    }
    __builtin_amdgcn_s_setprio(1);
#pragma unroll
    for (int kk = 0; kk < 4; ++kk) {
      const bf16x8 kv = u4_bf16x8(C[kk]);
      const bf16x8 lv = u4_bf16x8(C[4 + kk]);
      sa = __builtin_amdgcn_mfma_f32_32x32x16_bf16(kv, qh[kk], sa, 0, 0, 0);
      sb = __builtin_amdgcn_mfma_f32_32x32x16_bf16(kv, ql[kk], sb, 0, 0, 0);
      if (kk < 2)
        sa = __builtin_amdgcn_mfma_f32_32x32x16_bf16(lv, qh[kk], sa, 0, 0, 0);
      else
        sb = __builtin_amdgcn_mfma_f32_32x32x16_bf16(lv, qh[kk], sb, 0, 0, 0);
    }
    __builtin_amdgcn_s_setprio(0);
#pragma unroll
    for (int r = 0; r < 16; ++r) sa[r] += sb[r];  // sa = st
    // row max: max3 tree + cross-half shuffle
    const float e0 = m3(sa[0], sa[1], sa[2]);
    const float e1 = m3(sa[3], sa[4], sa[5]);
    const float e2 = m3(sa[6], sa[7], sa[8]);
    const float e3 = m3(sa[9], sa[10], sa[11]);
    const float e4 = m3(sa[12], sa[13], sa[14]);
    float pmax = fmaxf(m3(e0, e1, e2), m3(e3, e4, sa[15]));
    pmax = fmaxf(pmax, __shfl_xor(pmax, 32));
    if (__any(pmax > m + THR)) {  // defer-max: rescale rarely
      const float mnew = fmaxf(m, pmax);
      const float sc = exp2_fast(m - mnew);
#pragma unroll
      for (int r = 0; r < 16; ++r) {
        a0[r] *= sc; a1[r] *= sc; a2[r] *= sc; a3[r] *= sc;
      }
      m = mnew;
    }
    // skip-tile fast path: whole tile's p < 2^-26 -> contributes <=6e-5 of l
    if (__any(pmax > m - SKIP)) {
      uint4 xv[8];
#pragma unroll
      for (int j = 0; j < 8; ++j)
        xv[j] = xfp[((tile * 2 + (j >> 2)) * 4 + (j & 3)) * 64 + lane];
      unsigned pg[4][2];
#pragma unroll
      for (int g = 0; g < 4; ++g) {
        pg[g][0] = cvt_pk_bf16(exp2_fast(sa[4 * g + 0] - m),
                               exp2_fast(sa[4 * g + 1] - m));
        pg[g][1] = cvt_pk_bf16(exp2_fast(sa[4 * g + 2] - m),
                               exp2_fast(sa[4 * g + 3] - m));
      }
      __builtin_amdgcn_s_setprio(1);
#pragma unroll
      for (int kk = 0; kk < 2; ++kk) {
        unsigned x0 = pg[2 * kk][0], y0 = pg[2 * kk + 1][0];
        unsigned x1 = pg[2 * kk][1], y1 = pg[2 * kk + 1][1];
        asm("v_permlane32_swap_b32 %0, %1" : "+v"(x0), "+v"(y0));
        asm("v_permlane32_swap_b32 %0, %1" : "+v"(x1), "+v"(y1));
        const bf16x8 pf = mk_bf16x8(x0, x1, y0, y1);
        a0 = __builtin_amdgcn_mfma_f32_32x32x16_bf16(u4_bf16x8(xv[kk * 4 + 0]),
                                                     pf, a0, 0, 0, 0);
        a1 = __builtin_amdgcn_mfma_f32_32x32x16_bf16(u4_bf16x8(xv[kk * 4 + 1]),
                                                     pf, a1, 0, 0, 0);
        a2 = __builtin_amdgcn_mfma_f32_32x32x16_bf16(u4_bf16x8(xv[kk * 4 + 2]),
                                                     pf, a2, 0, 0, 0);
        a3 = __builtin_amdgcn_mfma_f32_32x32x16_bf16(u4_bf16x8(xv[kk * 4 + 3]),
                                                     pf, a3, 0, 0, 0);
      }
      __builtin_amdgcn_s_setprio(0);
    }
  };

  for (int i = 0; i < 32; i += 2) {
    body(KA, KB, i);
    body(KB, KA, i + 1);
  }

  // -------- merge the 4 waves' partial (m, acc^T) in LDS. l is acc row 127.
  __shared__ float mbuf[4][32];
  __shared__ float accbuf[128 * 33];
  if (lane < 32) mbuf[wave][col] = m;
  __syncthreads();
  const float mstar = fmaxf(fmaxf(mbuf[0][col], mbuf[1][col]),
                            fmaxf(mbuf[2][col], mbuf[3][col]));
  const float wsc = exp2_fast(m - mstar);
  auto emit = [&](const f32x16& av, int fb, bool first) {
#pragma unroll
    for (int r = 0; r < 16; ++r) {
      const int f = fb * 32 + (r & 3) + 8 * (r >> 2) + 4 * half;
      const float v = av[r] * wsc;
      if (first) accbuf[f * 33 + col] = v;
      else accbuf[f * 33 + col] += v;
    }
  };
  for (int p = 0; p < 4; ++p) {
    if (wave == p) {
      const bool first = (p == 0);
      emit(a0, 0, first);
      emit(a1, 1, first);
      emit(a2, 2, first);
      emit(a3, 3, first);
    }
    __syncthreads();
  }

  // readout: 256 threads, q = tid>>3 (32 rows), fg = tid&7 (16 f each)
  const int q = tid >> 3;
  const int fg = tid & 7;
  const float inv = 1.0f / accbuf[127 * 33 + q];
  float* ob = out + ((long)(b * S_DIM + q0 + q)) * F_DIM;
#pragma unroll
  for (int j = 0; j < 16; ++j) {
    const int f = fg * 16 + j;
    if (f < F_DIM) ob[f] = accbuf[f * 33 + q] * inv;
  }
}

extern "C" void kernel_launch(void* const* d_in, const int* in_sizes, int n_in,
                              void* d_out, int out_size, void* d_ws,
                              size_t ws_size, hipStream_t stream) {
  const float* x1 = (const float*)d_in[0];
  const float* x2 = (const float*)d_in[1];
  const float* W = (const float*)d_in[2];
  const float* bias = (const float*)d_in[3];
  float* out = (float*)d_out;

  char* ws = (char*)d_ws;
  uint4* qhf = (uint4*)ws;                     // 2 MB
  uint4* qlf = (uint4*)(ws + (2l << 20));      // 2 MB
  uint4* khf = (uint4*)(ws + (4l << 20));      // 2 MB
  uint4* klf = (uint4*)(ws + (6l << 20));      // 2 MB
  uint4* x2tf = (uint4*)(ws + (8l << 20));     // 4 MB

  hipLaunchKernelGGL(prep_kernel, dim3(1280), dim3(256), 0, stream, x1, x2, W,
                     bias, qhf, qlf, khf, klf, x2tf);
  hipLaunchKernelGGL(attn_kernel, dim3(512), dim3(256), 0, stream, qhf, qlf,
                     khf, klf, x2tf, out);
}